// Round 3
// baseline (465.339 us; speedup 1.0000x reference)
//
#include <hip/hip_runtime.h>

// Decoder: 12 sequential steps of {attention over 12 enc timesteps, GRU cell, linear->scalar, feedback}.
// B=65536 batch elements independent -> block owns 16 batch elems, 16 lanes per b, 4 dims per lane.
// R8: attack the AGPR-shuttle storm + the real bank conflict.
//  - R7 counters: VALUBusy 61% x 267us => ~1000 VALU instr/step-lane vs ~330 in source. VGPR_Count=88
//    with ~170 live regs => allocator parks VALU-used values (e4[48]!) in AGPR, v_accvgpr_read per use.
//    Fix: pin all 16 MFMA B-frags (80 regs) to AGPR explicitly ("+a" asm). MFMA reads B from AGPR
//    directly (gfx950 unified file) so this is free, and it vacates arch VGPRs for e4/h/softmax.
//  - sHi/sLo stride was 96 halves = 48 words == 16 mod 32 banks -> 8-way conflict on every A-frag
//    ds_read_b128 (8 lanes/bank). Stride -> 104 halves (52 words == 20 mod 32, gcd 4 -> <=4-way),
//    still 16B-aligned.
//  - Kept from R7: input-side GRU + ALL biases folded into MFMA chunk 2 (A=[h|l0,l1,l2,1|pad]),
//    B cols = 256 [R|Z|NH|NI]; biases ride k-row 67.

#define TT 12     // T_IN == T_OUT == 12
#define BB 65536
#define HH 64
#define SROW 104  // sHi/sLo row stride in halves: 52 words, 20 mod 32 banks -> <=4-way conflicts

typedef _Float16 half8 __attribute__((ext_vector_type(8)));
typedef _Float16 half4 __attribute__((ext_vector_type(4)));
typedef float    f32x4 __attribute__((ext_vector_type(4)));
typedef float    f32x2 __attribute__((ext_vector_type(2)));

#define L2E 1.44269504088896f

__device__ __forceinline__ float ex2(float x){ return __builtin_amdgcn_exp2f(x); }
__device__ __forceinline__ float sigm(float x){ return 1.0f/(1.0f + ex2(-L2E*x)); }
__device__ __forceinline__ float tanh_(float x){ return 1.0f - 2.0f/(ex2(2.0f*L2E*x)+1.0f); }

// Pin a value into the AGPR file (free for MFMA A/B operands on gfx950; vacates arch VGPRs).
#define PIN_A(x) asm volatile("" : "+a"(x))

// DPP row_ror rotate-reduce within the 16-lane row: after ror:1,2,4,8 every lane holds the row sum.
// update_dpp intrinsic => compiler handles DPP hazards and fuses mov_dpp+add where legal.
template<int N>
__device__ __forceinline__ float ror_add(float x){
    int s = __builtin_amdgcn_update_dpp(0, __float_as_int(x), 0x120+N, 0xF, 0xF, false);
    return x + __int_as_float(s);
}
__device__ __forceinline__ float sum16(float x){
    x = ror_add<1>(x); x = ror_add<2>(x); x = ror_add<4>(x); x = ror_add<8>(x);
    return x;
}

__device__ __forceinline__ float max3f(float a, float b, float c){
    return fmaxf(fmaxf(a,b),c);   // clang folds to v_max3_f32
}

#define MFMA16(A,B,C) __builtin_amdgcn_mfma_f32_16x16x32_f16(A,B,C,0,0,0)

__global__ __launch_bounds__(256, 2)
void decoder_kernel(const float* __restrict__ enc,    // (12,B,64)
                    const float* __restrict__ hid0,   // (B,64)
                    const float* __restrict__ last0,  // (B,3)
                    const float* __restrict__ Wih,    // (192,3)
                    const float* __restrict__ Whh,    // (192,64)
                    const float* __restrict__ bih,    // (192)
                    const float* __restrict__ bhh,    // (192)
                    const float* __restrict__ Wlin,   // (64)
                    const float* __restrict__ blin,   // (1)
                    float* __restrict__ out)          // (B,12)
{
    // A-staging rows: [h(64) | lst(4) | zero-pad] hi + lo residual. stride SROW halves.
    __shared__ __align__(16) _Float16 sHi[16*SROW];
    __shared__ __align__(16) _Float16 sLo[16*SROW];
    // Gate pre-activations: 16 batch rows x [R(64) | Z(64) | NH(64) | NI(64)], stride 260 floats.
    __shared__ __align__(16) float    sGh[16*260];

    const int tid  = threadIdx.x;
    const int wv   = tid >> 6;        // wave 0..3
    const int lane = tid & 63;
    const int q    = lane & 15;       // dim group / MFMA n or m index
    const int quad = lane >> 4;       // which batch elem of this wave (attn phase) / k-subchunk (MFMA)
    const int m    = wv*4 + quad;     // batch row within block, 0..15
    const size_t b = (size_t)blockIdx.x*16 + m;
    const int jq   = wv*16 + q;       // this lane's output column within each 64-col gate region

    // one-time zero of the pad region (halves 68..SROW-1 of each row) so chunk-2 A-frags of
    // quads 1..3 read zeros. Visibility guaranteed by the step-0 __syncthreads.
    for (int i = tid; i < 16*SROW; i += 256){
        if ((i % SROW) >= 68){ sHi[i] = (_Float16)0; sLo[i] = (_Float16)0; }
    }

    // ---- one-time loads (register-resident) ----
    f32x4 e4[TT];
    #pragma unroll
    for (int t=0;t<TT;++t)
        e4[t] = *(const f32x4*)(enc + ((size_t)t*BB + b)*HH + 4*q);

    f32x4 h = *(const f32x4*)(hid0 + b*HH + 4*q);
    float l0 = last0[b*3+0], l1 = last0[b*3+1], l2 = last0[b*3+2];
    float bl = blin[0];
    f32x4 wl = *(const f32x4*)(Wlin + 4*q);

    // W_hh^T B-fragments, hi/lo fp16 split (k-chunks 0,1), per gate region.
    // B-frag layout: n = lane&15 (col jq), k = kc*32 + quad*8 + jj.
    half8 bR0h,bR0l,bR1h,bR1l, bZ0h,bZ0l,bZ1h,bZ1l, bN0h,bN0l,bN1h,bN1l;
    {
        #pragma unroll
        for (int g=0; g<3; ++g){
            int row = g*64 + jq;      // Whh row: r / z / n
            #pragma unroll
            for (int kc=0; kc<2; ++kc){
                const float* src = Whh + row*64 + kc*32 + quad*8;
                half8 vh, vl;
                #pragma unroll
                for (int jj=0;jj<8;++jj){
                    float w = src[jj];
                    _Float16 whi = (_Float16)w;
                    vh[jj] = whi;
                    vl[jj] = (_Float16)(w - (float)whi);
                }
                if (g==0){ if(kc==0){bR0h=vh;bR0l=vl;} else {bR1h=vh;bR1l=vl;} }
                else if (g==1){ if(kc==0){bZ0h=vh;bZ0l=vl;} else {bZ1h=vh;bZ1l=vl;} }
                else { if(kc==0){bN0h=vh;bN0l=vl;} else {bN1h=vh;bN1l=vl;} }
            }
        }
    }
    // chunk-2 B-frags: rows k=64..67 hold [Wih col0..2 | bias]; only quad==0 lanes nonzero.
    half8 bR2h, bZ2h, bN2h, bI2h;
    #pragma unroll
    for (int jj=0;jj<8;++jj){ bR2h[jj]=(_Float16)0; bZ2h[jj]=(_Float16)0; bN2h[jj]=(_Float16)0; bI2h[jj]=(_Float16)0; }
    if (quad == 0){
        #pragma unroll
        for (int jj=0;jj<3;++jj){
            bR2h[jj] = (_Float16)Wih[(      jq)*3 + jj];
            bZ2h[jj] = (_Float16)Wih[( 64 + jq)*3 + jj];
            bI2h[jj] = (_Float16)Wih[(128 + jq)*3 + jj];
        }
        bR2h[3] = (_Float16)(bih[      jq] + bhh[      jq]);
        bZ2h[3] = (_Float16)(bih[ 64 + jq] + bhh[ 64 + jq]);
        bN2h[3] = (_Float16)(bhh[128 + jq]);
        bI2h[3] = (_Float16)(bih[128 + jq]);
    }

    // Pin all MFMA-only B operands into AGPRs: frees ~80 arch VGPRs for e4/h/softmax temps,
    // eliminating v_accvgpr shuttling of VALU-used values.
    PIN_A(bR0h); PIN_A(bR0l); PIN_A(bR1h); PIN_A(bR1l);
    PIN_A(bZ0h); PIN_A(bZ0l); PIN_A(bZ1h); PIN_A(bZ1l);
    PIN_A(bN0h); PIN_A(bN0l); PIN_A(bN1h); PIN_A(bN1l);
    PIN_A(bR2h); PIN_A(bZ2h); PIN_A(bN2h); PIN_A(bI2h);

    // ---- 12 sequential decoder steps ----
    for (int s=0;s<TT;++s){
        // attention logits: packed dot + DPP rotate-reduce
        float a[TT];
        #pragma unroll
        for (int t=0;t<TT;++t){
            f32x2 p2 = e4[t].xy * h.xy;
            p2 += e4[t].zw * h.zw;
            a[t] = sum16(p2.x + p2.y);
        }
        // max via v_max3 triples
        float m0 = max3f(a[0],a[1],a[2]),  m1 = max3f(a[3],a[4],a[5]);
        float m2 = max3f(a[6],a[7],a[8]),  m3 = max3f(a[9],a[10],a[11]);
        float mx = fmaxf(max3f(m0,m1,m2), m3);
        float nm = -mx*L2E;
        #pragma unroll
        for (int t=0;t<TT;++t) a[t] = ex2(__builtin_fmaf(a[t], L2E, nm));
        // sum (tree)
        float s01=a[0]+a[1], s23=a[2]+a[3], s45=a[4]+a[5], s67=a[6]+a[7], s89=a[8]+a[9], sab=a[10]+a[11];
        float ss = ((s01+s23)+(s45+s67)) + (s89+sab);
        float inv = 1.0f/ss;
        // context: dual f32x4 accumulators (v_pk_fma_f32), then h += ctx*inv
        f32x4 ctxA = {0.f,0.f,0.f,0.f}, ctxB = {0.f,0.f,0.f,0.f};
        #pragma unroll
        for (int t=0;t<TT;t+=2){
            ctxA += e4[t]   * (f32x4)(a[t]);
            ctxB += e4[t+1] * (f32x4)(a[t+1]);
        }
        h += (ctxA + ctxB) * (f32x4)(inv);

        // stage h into LDS as fp16 hi + lo residual (~2^-22 combined)
        half4 hhi, hlo;
        #pragma unroll
        for (int j=0;j<4;++j){
            _Float16 hh = (_Float16)h[j];
            hhi[j] = hh;
            hlo[j] = (_Float16)(h[j] - (float)hh);
        }
        *(half4*)&sHi[m*SROW + 4*q] = hhi;
        *(half4*)&sLo[m*SROW + 4*q] = hlo;
        // stage lst (+the bias lane's 1.0) at halves 64..67
        if (q == 0){
            _Float16 a0=(_Float16)l0, a1=(_Float16)l1, a2=(_Float16)l2;
            half4 th = {a0, a1, a2, (_Float16)1.0f};
            half4 tl = {(_Float16)(l0-(float)a0), (_Float16)(l1-(float)a1),
                        (_Float16)(l2-(float)a2), (_Float16)0.0f};
            *(half4*)&sHi[m*SROW + 64] = th;
            *(half4*)&sLo[m*SROW + 64] = tl;
        }
        __syncthreads();

        // MFMA: pre-acts for 16 batch rows x 256 cols [R|Z|NH|NI], k = [h(64) | lst,1 | pad].
        // A-frag: row = lane&15 (=q), k = kc*32 + quad*8 + jj.
        half8 ahi0 = *(half8*)&sHi[q*SROW +  0 + quad*8];
        half8 ahi1 = *(half8*)&sHi[q*SROW + 32 + quad*8];
        half8 ahi2 = *(half8*)&sHi[q*SROW + 64 + quad*8];
        half8 alo0 = *(half8*)&sLo[q*SROW +  0 + quad*8];
        half8 alo1 = *(half8*)&sLo[q*SROW + 32 + quad*8];
        half8 alo2 = *(half8*)&sLo[q*SROW + 64 + quad*8];

        // R region (cols 0..63): hidden hi/lo 3-term + input/bias chunk (hi + lo contributions)
        {
            f32x4 acc = {0.f,0.f,0.f,0.f};
            acc = MFMA16(ahi0,bR0h,acc); acc = MFMA16(ahi1,bR1h,acc);
            acc = MFMA16(ahi0,bR0l,acc); acc = MFMA16(ahi1,bR1l,acc);
            acc = MFMA16(alo0,bR0h,acc); acc = MFMA16(alo1,bR1h,acc);
            acc = MFMA16(ahi2,bR2h,acc); acc = MFMA16(alo2,bR2h,acc);
            #pragma unroll
            for (int r=0;r<4;++r) sGh[(quad*4+r)*260 +   0 + jq] = acc[r];
        }
        // Z region (cols 64..127)
        {
            f32x4 acc = {0.f,0.f,0.f,0.f};
            acc = MFMA16(ahi0,bZ0h,acc); acc = MFMA16(ahi1,bZ1h,acc);
            acc = MFMA16(ahi0,bZ0l,acc); acc = MFMA16(ahi1,bZ1l,acc);
            acc = MFMA16(alo0,bZ0h,acc); acc = MFMA16(alo1,bZ1h,acc);
            acc = MFMA16(ahi2,bZ2h,acc); acc = MFMA16(alo2,bZ2h,acc);
            #pragma unroll
            for (int r=0;r<4;++r) sGh[(quad*4+r)*260 +  64 + jq] = acc[r];
        }
        // NH region (cols 128..191): hidden side + b_hh_n (rides ahi2's 1.0 lane)
        {
            f32x4 acc = {0.f,0.f,0.f,0.f};
            acc = MFMA16(ahi0,bN0h,acc); acc = MFMA16(ahi1,bN1h,acc);
            acc = MFMA16(ahi0,bN0l,acc); acc = MFMA16(ahi1,bN1l,acc);
            acc = MFMA16(alo0,bN0h,acc); acc = MFMA16(alo1,bN1h,acc);
            acc = MFMA16(ahi2,bN2h,acc);
            #pragma unroll
            for (int r=0;r<4;++r) sGh[(quad*4+r)*260 + 128 + jq] = acc[r];
        }
        // NI region (cols 192..255): input side only (Wih_n * lst + b_ih_n)
        {
            f32x4 acc = {0.f,0.f,0.f,0.f};
            acc = MFMA16(ahi2,bI2h,acc); acc = MFMA16(alo2,bI2h,acc);
            #pragma unroll
            for (int r=0;r<4;++r) sGh[(quad*4+r)*260 + 192 + jq] = acc[r];
        }
        __syncthreads();

        // gates: r=sig(R), z=sig(Z), n=tanh(NI + r*NH), h'=(1-z)n+z*h  (pre-acts incl. biases)
        f32x4 gR  = *(f32x4*)&sGh[m*260 +   0 + 4*q];
        f32x4 gZ  = *(f32x4*)&sGh[m*260 +  64 + 4*q];
        f32x4 gNH = *(f32x4*)&sGh[m*260 + 128 + 4*q];
        f32x4 gNI = *(f32x4*)&sGh[m*260 + 192 + 4*q];

        float o = 0.f;
        #pragma unroll
        for (int j=0;j<4;++j){
            float r = sigm(gR[j]);
            float z = sigm(gZ[j]);
            float n = tanh_(gNI[j] + r*gNH[j]);
            float hn = (1.f - z)*n + z*h[j];
            h[j] = hn;
            o += hn * wl[j];
        }
        // out = h' . W_lin + b_lin, DPP rotate-reduce over 16-lane group
        o = sum16(o) + bl;
        if (q == 0) out[b*TT + s] = o;
        // last = [out, last[0], last[1]]
        l2 = l1; l1 = l0; l0 = o;
    }
}

extern "C" void kernel_launch(void* const* d_in, const int* in_sizes, int n_in,
                              void* d_out, int out_size, void* d_ws, size_t ws_size,
                              hipStream_t stream)
{
    const float* enc  = (const float*)d_in[0];
    const float* hid0 = (const float*)d_in[1];
    const float* lst  = (const float*)d_in[2];
    const float* Wih  = (const float*)d_in[3];
    const float* Whh  = (const float*)d_in[4];
    const float* bih  = (const float*)d_in[5];
    const float* bhh  = (const float*)d_in[6];
    const float* Wlin = (const float*)d_in[7];
    const float* blin = (const float*)d_in[8];
    decoder_kernel<<<BB/16, 256, 0, stream>>>(enc, hid0, lst, Wih, Whh, bih, bhh,
                                              Wlin, blin, (float*)d_out);
}

// Round 5
// 455.090 us; speedup vs baseline: 1.0225x; 1.0225x over previous
//
#include <hip/hip_runtime.h>

// Decoder: 12 sequential steps of {attention over 12 enc timesteps, GRU cell, linear->scalar, feedback}.
// B=65536, block = 16 batch elems, 4 waves. Two layouts per step:
//   phase A (elem-major): lane(q,quad) of wave wv owns elem m=wv*4+quad, dims 4q..4q+3.
//   phase B (row/col):    lane(q,quad) of wave wv owns rows quad*4+r (r=0..3), col jq=wv*16+q.
// R10 = R9 + restored lst-lo MFMA terms (R9 failed absmax 0.4766 vs 0.4625 threshold: lst is the
// fed-back OUTPUT, magnitude ~1-5, so lst_lo ~2e-3; dropping alo2*Wih lost few-e-4 per gate
// pre-activation, amplified by 12 feedback steps 0.30->0.48).
// R9 structure kept: sGh deleted (it was the bank-conflict source: SQ_LDS_BANK_CONFLICT scaled
// exactly with sGh traffic across R5b/R7/R8, ignored sHi stride changes). Gates evaluated
// IN-REGISTER in (row,col) layout after the MFMAs; only h' round-trips through a stride-65 fp32
// buffer (odd stride = conflict-free b32). out/feedback reduction moved into next step's phase A.
// Biases ride TWO 1.0 columns (k=67 hi, k=68 lo). __launch_bounds__(256,3) targets 3 blocks/CU.

#define TT 12     // T_IN == T_OUT == 12
#define BB 65536
#define HH 64
#define SROW 104  // sHi/sLo row stride in halves (52 words, 20 mod 32 banks)
#define HFS 65    // sHf row stride in floats: odd -> all b32 access conflict-free

typedef _Float16 half8 __attribute__((ext_vector_type(8)));
typedef _Float16 half4 __attribute__((ext_vector_type(4)));
typedef float    f32x4 __attribute__((ext_vector_type(4)));
typedef float    f32x2 __attribute__((ext_vector_type(2)));

#define L2E 1.44269504088896f

__device__ __forceinline__ float ex2(float x){ return __builtin_amdgcn_exp2f(x); }
__device__ __forceinline__ float sigm(float x){ return 1.0f/(1.0f + ex2(-L2E*x)); }
__device__ __forceinline__ float tanh_(float x){ return 1.0f - 2.0f/(ex2(2.0f*L2E*x)+1.0f); }

// DPP row_ror rotate-reduce within the 16-lane row (hazard-safe intrinsic form).
template<int N>
__device__ __forceinline__ float ror_add(float x){
    int s = __builtin_amdgcn_update_dpp(0, __float_as_int(x), 0x120+N, 0xF, 0xF, false);
    return x + __int_as_float(s);
}
__device__ __forceinline__ float sum16(float x){
    x = ror_add<1>(x); x = ror_add<2>(x); x = ror_add<4>(x); x = ror_add<8>(x);
    return x;
}

__device__ __forceinline__ float max3f(float a, float b, float c){
    return fmaxf(fmaxf(a,b),c);   // clang folds to v_max3_f32
}

#define MFMA16(A,B,C) __builtin_amdgcn_mfma_f32_16x16x32_f16(A,B,C,0,0,0)

__global__ __launch_bounds__(256, 3)
void decoder_kernel(const float* __restrict__ enc,    // (12,B,64)
                    const float* __restrict__ hid0,   // (B,64)
                    const float* __restrict__ last0,  // (B,3)
                    const float* __restrict__ Wih,    // (192,3)
                    const float* __restrict__ Whh,    // (192,64)
                    const float* __restrict__ bih,    // (192)
                    const float* __restrict__ bhh,    // (192)
                    const float* __restrict__ Wlin,   // (64)
                    const float* __restrict__ blin,   // (1)
                    float* __restrict__ out)          // (B,12)
{
    // A rows: [h_att(64) | l0,l1,l2,1,1 | zero(69..103)] fp16 hi + lo residual.
    __shared__ __align__(16) _Float16 sHi[16*SROW];
    __shared__ __align__(16) _Float16 sLo[16*SROW];
    // fp32 hidden round-trip buffer [16 elems][64 dims], stride 65 (odd -> conflict-free).
    __shared__ __align__(16) float    sHf[16*HFS];

    const int tid  = threadIdx.x;
    const int wv   = tid >> 6;
    const int lane = tid & 63;
    const int q    = lane & 15;
    const int quad = lane >> 4;
    const int m    = wv*4 + quad;       // phase-A elem, 0..15
    const size_t b = (size_t)blockIdx.x*16 + m;
    const int jq   = wv*16 + q;         // phase-B column, 0..63
    const int grow = quad*4;            // phase-B row base (C/D: row = quad*4 + reg)

    // one-time zero of pad halves (>=69) in BOTH sHi and sLo: phase-B chunk-2 A-frags of quads
    // 1..3 read halves 72..95 -> must be exact zeros (stale bytes could be fp16-NaN; NaN*0=NaN).
    // Halves 64..68 are rewritten by q==0 every step. Visible after step-0's barrier 1.
    for (int i = tid; i < 16*SROW; i += 256)
        if ((i % SROW) >= 69){ sHi[i] = (_Float16)0; sLo[i] = (_Float16)0; }

    // ---- one-time loads ----
    f32x4 e4[TT];
    #pragma unroll
    for (int t=0;t<TT;++t)
        e4[t] = *(const f32x4*)(enc + ((size_t)t*BB + b)*HH + 4*q);

    f32x4 h = *(const f32x4*)(hid0 + b*HH + 4*q);          // phase-A hidden (elem-major)
    float l0 = last0[b*3+0], l1 = last0[b*3+1], l2 = last0[b*3+2];
    float bl = blin[0];
    f32x4 wl = *(const f32x4*)(Wlin + 4*q);

    // W_hh^T B-frags, hi/lo fp16 (k-chunks 0,1) per gate. n=lane&15 (col jq), k=kc*32+quad*8+jj.
    half8 bR0h,bR0l,bR1h,bR1l, bZ0h,bZ0l,bZ1h,bZ1l, bN0h,bN0l,bN1h,bN1l;
    {
        #pragma unroll
        for (int g=0; g<3; ++g){
            int row = g*64 + jq;
            #pragma unroll
            for (int kc=0; kc<2; ++kc){
                const float* src = Whh + row*64 + kc*32 + quad*8;
                half8 vh, vl;
                #pragma unroll
                for (int jj=0;jj<8;++jj){
                    float w = src[jj];
                    _Float16 whi = (_Float16)w;
                    vh[jj] = whi;
                    vl[jj] = (_Float16)(w - (float)whi);
                }
                if (g==0){ if(kc==0){bR0h=vh;bR0l=vl;} else {bR1h=vh;bR1l=vl;} }
                else if (g==1){ if(kc==0){bZ0h=vh;bZ0l=vl;} else {bZ1h=vh;bZ1l=vl;} }
                else { if(kc==0){bN0h=vh;bN0l=vl;} else {bN1h=vh;bN1l=vl;} }
            }
        }
    }
    // chunk-2 B-frags: k=64..66 -> Wih cols, k=67 -> bias_hi (A=1), k=68 -> bias_lo (A=1).
    // Only quad==0 lanes (k=64..71) are nonzero.
    half8 bR2, bZ2, bN2, bI2;
    #pragma unroll
    for (int jj=0;jj<8;++jj){ bR2[jj]=(_Float16)0; bZ2[jj]=(_Float16)0; bN2[jj]=(_Float16)0; bI2[jj]=(_Float16)0; }
    if (quad == 0){
        #pragma unroll
        for (int jj=0;jj<3;++jj){
            bR2[jj] = (_Float16)Wih[(      jq)*3 + jj];
            bZ2[jj] = (_Float16)Wih[( 64 + jq)*3 + jj];
            bI2[jj] = (_Float16)Wih[(128 + jq)*3 + jj];
        }
        float br = bih[      jq] + bhh[      jq];
        float bz = bih[ 64 + jq] + bhh[ 64 + jq];
        float bn = bhh[128 + jq];
        float bi = bih[128 + jq];
        _Float16 brh=(_Float16)br, bzh=(_Float16)bz, bnh=(_Float16)bn, bih_=(_Float16)bi;
        bR2[3]=brh; bR2[4]=(_Float16)(br-(float)brh);
        bZ2[3]=bzh; bZ2[4]=(_Float16)(bz-(float)bzh);
        bN2[3]=bnh; bN2[4]=(_Float16)(bn-(float)bnh);
        bI2[3]=bih_; bI2[4]=(_Float16)(bi-(float)bih_);
    }

    // ---- 12 sequential decoder steps ----
    for (int s=0;s<TT;++s){
        // ===== phase A (elem-major) =====
        if (s > 0){
            // read back h' of step s-1; emit out[s-1] and feedback.
            h[0] = sHf[m*HFS + 4*q + 0];
            h[1] = sHf[m*HFS + 4*q + 1];
            h[2] = sHf[m*HFS + 4*q + 2];
            h[3] = sHf[m*HFS + 4*q + 3];
            float o = h[0]*wl[0] + h[1]*wl[1] + h[2]*wl[2] + h[3]*wl[3];
            o = sum16(o) + bl;
            if (q == 0) out[b*TT + (s-1)] = o;
            l2 = l1; l1 = l0; l0 = o;
        }
        // attention logits
        float a[TT];
        #pragma unroll
        for (int t=0;t<TT;++t){
            f32x2 p2 = e4[t].xy * h.xy;
            p2 += e4[t].zw * h.zw;
            a[t] = sum16(p2.x + p2.y);
        }
        float m0 = max3f(a[0],a[1],a[2]),  m1 = max3f(a[3],a[4],a[5]);
        float m2 = max3f(a[6],a[7],a[8]),  m3 = max3f(a[9],a[10],a[11]);
        float mx = fmaxf(max3f(m0,m1,m2), m3);
        float nm = -mx*L2E;
        #pragma unroll
        for (int t=0;t<TT;++t) a[t] = ex2(__builtin_fmaf(a[t], L2E, nm));
        float s01=a[0]+a[1], s23=a[2]+a[3], s45=a[4]+a[5], s67=a[6]+a[7], s89=a[8]+a[9], sab=a[10]+a[11];
        float ss = ((s01+s23)+(s45+s67)) + (s89+sab);
        float inv = 1.0f/ss;
        f32x4 ctxA = {0.f,0.f,0.f,0.f}, ctxB = {0.f,0.f,0.f,0.f};
        #pragma unroll
        for (int t=0;t<TT;t+=2){
            ctxA += e4[t]   * (f32x4)(a[t]);
            ctxB += e4[t+1] * (f32x4)(a[t+1]);
        }
        h += (ctxA + ctxB) * (f32x4)(inv);    // h_att

        // stage h_att: fp16 hi+lo for MFMA, fp32 for the gate z*h term
        half4 hhi, hlo;
        #pragma unroll
        for (int j=0;j<4;++j){
            _Float16 hh = (_Float16)h[j];
            hhi[j] = hh;
            hlo[j] = (_Float16)(h[j] - (float)hh);
        }
        *(half4*)&sHi[m*SROW + 4*q] = hhi;
        *(half4*)&sLo[m*SROW + 4*q] = hlo;
        sHf[m*HFS + 4*q + 0] = h[0];
        sHf[m*HFS + 4*q + 1] = h[1];
        sHf[m*HFS + 4*q + 2] = h[2];
        sHf[m*HFS + 4*q + 3] = h[3];
        if (q == 0){
            _Float16 a0=(_Float16)l0, a1=(_Float16)l1, a2=(_Float16)l2;
            half4 th = {a0, a1, a2, (_Float16)1.0f};
            // lst lo residual (lst = fed-back outputs, magnitude ~1-5 -> lo ~2e-3, matters
            // through 12-step feedback); lo of the 1.0 bias columns is exactly 0.
            half4 tl = {(_Float16)(l0-(float)a0), (_Float16)(l1-(float)a1),
                        (_Float16)(l2-(float)a2), (_Float16)0.0f};
            *(half4*)&sHi[m*SROW + 64] = th;
            *(half4*)&sLo[m*SROW + 64] = tl;
            sHi[m*SROW + 68] = (_Float16)1.0f;   // second 1.0 -> bias_lo column k=68
            sLo[m*SROW + 68] = (_Float16)0.0f;
        }
        __syncthreads();   // barrier 1

        // ===== phase B (row/col): MFMA + in-register gates =====
        half8 ahi0 = *(half8*)&sHi[q*SROW +  0 + quad*8];
        half8 ahi1 = *(half8*)&sHi[q*SROW + 32 + quad*8];
        half8 ahi2 = *(half8*)&sHi[q*SROW + 64 + quad*8];
        half8 alo0 = *(half8*)&sLo[q*SROW +  0 + quad*8];
        half8 alo1 = *(half8*)&sLo[q*SROW + 32 + quad*8];
        half8 alo2 = *(half8*)&sLo[q*SROW + 64 + quad*8];

        f32x4 accR = {0.f,0.f,0.f,0.f};
        accR = MFMA16(ahi0,bR0h,accR); accR = MFMA16(ahi1,bR1h,accR);
        accR = MFMA16(ahi0,bR0l,accR); accR = MFMA16(ahi1,bR1l,accR);
        accR = MFMA16(alo0,bR0h,accR); accR = MFMA16(alo1,bR1h,accR);
        accR = MFMA16(ahi2,bR2 ,accR); accR = MFMA16(alo2,bR2 ,accR);

        f32x4 accZ = {0.f,0.f,0.f,0.f};
        accZ = MFMA16(ahi0,bZ0h,accZ); accZ = MFMA16(ahi1,bZ1h,accZ);
        accZ = MFMA16(ahi0,bZ0l,accZ); accZ = MFMA16(ahi1,bZ1l,accZ);
        accZ = MFMA16(alo0,bZ0h,accZ); accZ = MFMA16(alo1,bZ1h,accZ);
        accZ = MFMA16(ahi2,bZ2 ,accZ); accZ = MFMA16(alo2,bZ2 ,accZ);

        f32x4 accN = {0.f,0.f,0.f,0.f};   // h_n + b_hh_n (no Wih entries -> no alo2 term needed)
        accN = MFMA16(ahi0,bN0h,accN); accN = MFMA16(ahi1,bN1h,accN);
        accN = MFMA16(ahi0,bN0l,accN); accN = MFMA16(ahi1,bN1l,accN);
        accN = MFMA16(alo0,bN0h,accN); accN = MFMA16(alo1,bN1h,accN);
        accN = MFMA16(ahi2,bN2 ,accN);

        f32x4 accI = {0.f,0.f,0.f,0.f};   // i_n = Wih_n*lst + b_ih_n
        accI = MFMA16(ahi2,bI2 ,accI); accI = MFMA16(alo2,bI2 ,accI);

        // h_att (fp32) at this lane's (row, col) cells
        float hA0 = sHf[(grow+0)*HFS + jq];
        float hA1 = sHf[(grow+1)*HFS + jq];
        float hA2 = sHf[(grow+2)*HFS + jq];
        float hA3 = sHf[(grow+3)*HFS + jq];
        float hAv[4] = {hA0,hA1,hA2,hA3};

        #pragma unroll
        for (int r=0;r<4;++r){
            float rg = sigm(accR[r]);
            float zg = sigm(accZ[r]);
            float ng = tanh_(accI[r] + rg*accN[r]);
            float hn = (1.f - zg)*ng + zg*hAv[r];
            sHf[(grow+r)*HFS + jq] = hn;    // own cells: read-then-write, no cross-lane hazard
        }
        __syncthreads();   // barrier 2
    }

    // epilogue: out for step 11
    {
        float h0 = sHf[m*HFS + 4*q + 0];
        float h1 = sHf[m*HFS + 4*q + 1];
        float h2 = sHf[m*HFS + 4*q + 2];
        float h3 = sHf[m*HFS + 4*q + 3];
        float o = h0*wl[0] + h1*wl[1] + h2*wl[2] + h3*wl[3];
        o = sum16(o) + bl;
        if (q == 0) out[b*TT + 11] = o;
    }
}

extern "C" void kernel_launch(void* const* d_in, const int* in_sizes, int n_in,
                              void* d_out, int out_size, void* d_ws, size_t ws_size,
                              hipStream_t stream)
{
    const float* enc  = (const float*)d_in[0];
    const float* hid0 = (const float*)d_in[1];
    const float* lst  = (const float*)d_in[2];
    const float* Wih  = (const float*)d_in[3];
    const float* Whh  = (const float*)d_in[4];
    const float* bih  = (const float*)d_in[5];
    const float* bhh  = (const float*)d_in[6];
    const float* Wlin = (const float*)d_in[7];
    const float* blin = (const float*)d_in[8];
    decoder_kernel<<<BB/16, 256, 0, stream>>>(enc, hid0, lst, Wih, Whh, bih, bhh,
                                              Wlin, blin, (float*)d_out);
}

// Round 6
// 420.722 us; speedup vs baseline: 1.1060x; 1.0817x over previous
//
#include <hip/hip_runtime.h>

// Decoder: 12 sequential steps of {attention over 12 enc timesteps, GRU cell, linear->scalar, feedback}.
// B=65536, block = 16 batch elems, 4 waves. Two layouts per step:
//   phase A (elem-major): lane(q,quad) of wave wv owns elem m=wv*4+quad, dims 4q..4q+3.
//   phase B (row/col):    lane(q,quad) of wave wv owns rows quad*4+r (r=0..3), col jq=wv*16+q.
// R11 = R10 with the phase-B register peak shaved under the (256,3) budget.
//  - R10 evidence: WRITE_SIZE 3.5->28.4MB + FETCH +9MB = scratch spills, appearing exactly when
//    launch_bounds(256,3) cut the unified budget to ~170/wave. Demand: 132 persistent (e4 48 +
//    B-frags 64 + misc 20) + phase-B working 40 (SIX A-frags live at once + 16 acc) = 172 > 170.
//    Occupancy gain 22->32% was exactly eaten by spill cost -> dur flat.
//  - Fix 1: chunk-major MFMA ordering. Each (ahi,alo) A-frag pair loads in its own scope, fires
//    its MFMAs, dies. A-frag liveness 24 -> 8 regs; phase-B peak ~156 < 170.
//  - Fix 2: fused exp/sum/context loop in phase A (consume a[t] at exponentiation) -> ~8 fewer
//    live regs at phase-A peak.
//  - Bank conflicts deprioritized: 11M cycles = 6.7%/CU, mostly hidden (R10 falsified the
//    conflict theory: removing sGh RAISED the counter; sHf stride-65 phase-B reads are 4-way).

#define TT 12     // T_IN == T_OUT == 12
#define BB 65536
#define HH 64
#define SROW 104  // sHi/sLo row stride in halves (52 words, 20 mod 32 banks)
#define HFS 65    // sHf row stride in floats: odd -> phase-A 2-way, phase-B <=4-way (acceptable)

typedef _Float16 half8 __attribute__((ext_vector_type(8)));
typedef _Float16 half4 __attribute__((ext_vector_type(4)));
typedef float    f32x4 __attribute__((ext_vector_type(4)));
typedef float    f32x2 __attribute__((ext_vector_type(2)));

#define L2E 1.44269504088896f

__device__ __forceinline__ float ex2(float x){ return __builtin_amdgcn_exp2f(x); }
__device__ __forceinline__ float sigm(float x){ return 1.0f/(1.0f + ex2(-L2E*x)); }
__device__ __forceinline__ float tanh_(float x){ return 1.0f - 2.0f/(ex2(2.0f*L2E*x)+1.0f); }

// DPP row_ror rotate-reduce within the 16-lane row (hazard-safe intrinsic form).
template<int N>
__device__ __forceinline__ float ror_add(float x){
    int s = __builtin_amdgcn_update_dpp(0, __float_as_int(x), 0x120+N, 0xF, 0xF, false);
    return x + __int_as_float(s);
}
__device__ __forceinline__ float sum16(float x){
    x = ror_add<1>(x); x = ror_add<2>(x); x = ror_add<4>(x); x = ror_add<8>(x);
    return x;
}

__device__ __forceinline__ float max3f(float a, float b, float c){
    return fmaxf(fmaxf(a,b),c);   // clang folds to v_max3_f32
}

#define MFMA16(A,B,C) __builtin_amdgcn_mfma_f32_16x16x32_f16(A,B,C,0,0,0)

__global__ __launch_bounds__(256, 3)
void decoder_kernel(const float* __restrict__ enc,    // (12,B,64)
                    const float* __restrict__ hid0,   // (B,64)
                    const float* __restrict__ last0,  // (B,3)
                    const float* __restrict__ Wih,    // (192,3)
                    const float* __restrict__ Whh,    // (192,64)
                    const float* __restrict__ bih,    // (192)
                    const float* __restrict__ bhh,    // (192)
                    const float* __restrict__ Wlin,   // (64)
                    const float* __restrict__ blin,   // (1)
                    float* __restrict__ out)          // (B,12)
{
    // A rows: [h_att(64) | l0,l1,l2,1,1 | zero(69..103)] fp16 hi + lo residual.
    __shared__ __align__(16) _Float16 sHi[16*SROW];
    __shared__ __align__(16) _Float16 sLo[16*SROW];
    // fp32 hidden round-trip buffer [16 elems][64 dims], stride 65.
    __shared__ __align__(16) float    sHf[16*HFS];

    const int tid  = threadIdx.x;
    const int wv   = tid >> 6;
    const int lane = tid & 63;
    const int q    = lane & 15;
    const int quad = lane >> 4;
    const int m    = wv*4 + quad;       // phase-A elem, 0..15
    const size_t b = (size_t)blockIdx.x*16 + m;
    const int jq   = wv*16 + q;         // phase-B column, 0..63
    const int grow = quad*4;            // phase-B row base (C/D: row = quad*4 + reg)

    // one-time zero of pad halves (>=69) in BOTH sHi and sLo (stale bytes could be fp16-NaN;
    // NaN*0=NaN). Halves 64..68 rewritten by q==0 every step. Visible after step-0's barrier 1.
    for (int i = tid; i < 16*SROW; i += 256)
        if ((i % SROW) >= 69){ sHi[i] = (_Float16)0; sLo[i] = (_Float16)0; }

    // ---- one-time loads ----
    f32x4 e4[TT];
    #pragma unroll
    for (int t=0;t<TT;++t)
        e4[t] = *(const f32x4*)(enc + ((size_t)t*BB + b)*HH + 4*q);

    f32x4 h = *(const f32x4*)(hid0 + b*HH + 4*q);          // phase-A hidden (elem-major)
    float l0 = last0[b*3+0], l1 = last0[b*3+1], l2 = last0[b*3+2];
    float bl = blin[0];
    f32x4 wl = *(const f32x4*)(Wlin + 4*q);

    // W_hh^T B-frags, hi/lo fp16 (k-chunks 0,1) per gate. n=lane&15 (col jq), k=kc*32+quad*8+jj.
    half8 bR0h,bR0l,bR1h,bR1l, bZ0h,bZ0l,bZ1h,bZ1l, bN0h,bN0l,bN1h,bN1l;
    {
        #pragma unroll
        for (int g=0; g<3; ++g){
            int row = g*64 + jq;
            #pragma unroll
            for (int kc=0; kc<2; ++kc){
                const float* src = Whh + row*64 + kc*32 + quad*8;
                half8 vh, vl;
                #pragma unroll
                for (int jj=0;jj<8;++jj){
                    float w = src[jj];
                    _Float16 whi = (_Float16)w;
                    vh[jj] = whi;
                    vl[jj] = (_Float16)(w - (float)whi);
                }
                if (g==0){ if(kc==0){bR0h=vh;bR0l=vl;} else {bR1h=vh;bR1l=vl;} }
                else if (g==1){ if(kc==0){bZ0h=vh;bZ0l=vl;} else {bZ1h=vh;bZ1l=vl;} }
                else { if(kc==0){bN0h=vh;bN0l=vl;} else {bN1h=vh;bN1l=vl;} }
            }
        }
    }
    // chunk-2 B-frags: k=64..66 -> Wih cols, k=67 -> bias_hi (A=1), k=68 -> bias_lo (A=1).
    // Only quad==0 lanes (k=64..71) are nonzero.
    half8 bR2, bZ2, bN2, bI2;
    #pragma unroll
    for (int jj=0;jj<8;++jj){ bR2[jj]=(_Float16)0; bZ2[jj]=(_Float16)0; bN2[jj]=(_Float16)0; bI2[jj]=(_Float16)0; }
    if (quad == 0){
        #pragma unroll
        for (int jj=0;jj<3;++jj){
            bR2[jj] = (_Float16)Wih[(      jq)*3 + jj];
            bZ2[jj] = (_Float16)Wih[( 64 + jq)*3 + jj];
            bI2[jj] = (_Float16)Wih[(128 + jq)*3 + jj];
        }
        float br = bih[      jq] + bhh[      jq];
        float bz = bih[ 64 + jq] + bhh[ 64 + jq];
        float bn = bhh[128 + jq];
        float bi = bih[128 + jq];
        _Float16 brh=(_Float16)br, bzh=(_Float16)bz, bnh=(_Float16)bn, bih_=(_Float16)bi;
        bR2[3]=brh; bR2[4]=(_Float16)(br-(float)brh);
        bZ2[3]=bzh; bZ2[4]=(_Float16)(bz-(float)bzh);
        bN2[3]=bnh; bN2[4]=(_Float16)(bn-(float)bnh);
        bI2[3]=bih_; bI2[4]=(_Float16)(bi-(float)bih_);
    }

    // ---- 12 sequential decoder steps ----
    for (int s=0;s<TT;++s){
        // ===== phase A (elem-major) =====
        if (s > 0){
            // read back h' of step s-1; emit out[s-1] and feedback.
            h[0] = sHf[m*HFS + 4*q + 0];
            h[1] = sHf[m*HFS + 4*q + 1];
            h[2] = sHf[m*HFS + 4*q + 2];
            h[3] = sHf[m*HFS + 4*q + 3];
            float o = h[0]*wl[0] + h[1]*wl[1] + h[2]*wl[2] + h[3]*wl[3];
            o = sum16(o) + bl;
            if (q == 0) out[b*TT + (s-1)] = o;
            l2 = l1; l1 = l0; l0 = o;
        }
        // attention logits
        float a[TT];
        #pragma unroll
        for (int t=0;t<TT;++t){
            f32x2 p2 = e4[t].xy * h.xy;
            p2 += e4[t].zw * h.zw;
            a[t] = sum16(p2.x + p2.y);
        }
        float m0 = max3f(a[0],a[1],a[2]),  m1 = max3f(a[3],a[4],a[5]);
        float m2 = max3f(a[6],a[7],a[8]),  m3 = max3f(a[9],a[10],a[11]);
        float mx = fmaxf(max3f(m0,m1,m2), m3);
        float nm = -mx*L2E;
        // fused exp + sum + context: a[t] consumed as it is exponentiated (lower reg peak)
        f32x4 ctxA = {0.f,0.f,0.f,0.f}, ctxB = {0.f,0.f,0.f,0.f};
        float ssA = 0.f, ssB = 0.f;
        #pragma unroll
        for (int t=0;t<TT;t+=2){
            float w0 = ex2(__builtin_fmaf(a[t],   L2E, nm));
            float w1 = ex2(__builtin_fmaf(a[t+1], L2E, nm));
            ctxA += e4[t]   * (f32x4)(w0);
            ctxB += e4[t+1] * (f32x4)(w1);
            ssA += w0; ssB += w1;
        }
        float inv = 1.0f/(ssA + ssB);
        h += (ctxA + ctxB) * (f32x4)(inv);    // h_att

        // stage h_att: fp16 hi+lo for MFMA, fp32 for the gate z*h term
        half4 hhi, hlo;
        #pragma unroll
        for (int j=0;j<4;++j){
            _Float16 hh = (_Float16)h[j];
            hhi[j] = hh;
            hlo[j] = (_Float16)(h[j] - (float)hh);
        }
        *(half4*)&sHi[m*SROW + 4*q] = hhi;
        *(half4*)&sLo[m*SROW + 4*q] = hlo;
        sHf[m*HFS + 4*q + 0] = h[0];
        sHf[m*HFS + 4*q + 1] = h[1];
        sHf[m*HFS + 4*q + 2] = h[2];
        sHf[m*HFS + 4*q + 3] = h[3];
        if (q == 0){
            _Float16 a0=(_Float16)l0, a1=(_Float16)l1, a2=(_Float16)l2;
            half4 th = {a0, a1, a2, (_Float16)1.0f};
            // lst lo residual (lst = fed-back outputs, magnitude ~1-5 -> lo ~2e-3, matters
            // through 12-step feedback); lo of the 1.0 bias columns is exactly 0.
            half4 tl = {(_Float16)(l0-(float)a0), (_Float16)(l1-(float)a1),
                        (_Float16)(l2-(float)a2), (_Float16)0.0f};
            *(half4*)&sHi[m*SROW + 64] = th;
            *(half4*)&sLo[m*SROW + 64] = tl;
            sHi[m*SROW + 68] = (_Float16)1.0f;   // second 1.0 -> bias_lo column k=68
            sLo[m*SROW + 68] = (_Float16)0.0f;
        }
        __syncthreads();   // barrier 1

        // ===== phase B (row/col): chunk-major MFMAs + in-register gates =====
        // A-frag pairs load in their own scope and die after their MFMAs: peak working set
        // = 8 A-frag regs + 16 acc regs (was 24 + 16 -> spilled at the 3-wave budget).
        f32x4 accR = {0.f,0.f,0.f,0.f};
        f32x4 accZ = {0.f,0.f,0.f,0.f};
        f32x4 accN = {0.f,0.f,0.f,0.f};
        f32x4 accI = {0.f,0.f,0.f,0.f};
        {   // k-chunk 0 (k=0..31)
            half8 ah = *(half8*)&sHi[q*SROW +  0 + quad*8];
            half8 al = *(half8*)&sLo[q*SROW +  0 + quad*8];
            accR = MFMA16(ah,bR0h,accR); accR = MFMA16(ah,bR0l,accR); accR = MFMA16(al,bR0h,accR);
            accZ = MFMA16(ah,bZ0h,accZ); accZ = MFMA16(ah,bZ0l,accZ); accZ = MFMA16(al,bZ0h,accZ);
            accN = MFMA16(ah,bN0h,accN); accN = MFMA16(ah,bN0l,accN); accN = MFMA16(al,bN0h,accN);
        }
        {   // k-chunk 1 (k=32..63)
            half8 ah = *(half8*)&sHi[q*SROW + 32 + quad*8];
            half8 al = *(half8*)&sLo[q*SROW + 32 + quad*8];
            accR = MFMA16(ah,bR1h,accR); accR = MFMA16(ah,bR1l,accR); accR = MFMA16(al,bR1h,accR);
            accZ = MFMA16(ah,bZ1h,accZ); accZ = MFMA16(ah,bZ1l,accZ); accZ = MFMA16(al,bZ1h,accZ);
            accN = MFMA16(ah,bN1h,accN); accN = MFMA16(ah,bN1l,accN); accN = MFMA16(al,bN1h,accN);
        }
        {   // k-chunk 2 (k=64..95): lst + bias columns
            half8 ah = *(half8*)&sHi[q*SROW + 64 + quad*8];
            half8 al = *(half8*)&sLo[q*SROW + 64 + quad*8];
            accR = MFMA16(ah,bR2,accR); accR = MFMA16(al,bR2,accR);
            accZ = MFMA16(ah,bZ2,accZ); accZ = MFMA16(al,bZ2,accZ);
            accN = MFMA16(ah,bN2,accN);
            accI = MFMA16(ah,bI2,accI); accI = MFMA16(al,bI2,accI);
        }

        // gates: r=sig(R), z=sig(Z), n=tanh(I + r*N), h'=(1-z)n+z*h_att
        #pragma unroll
        for (int r=0;r<4;++r){
            float rg = sigm(accR[r]);
            float zg = sigm(accZ[r]);
            float ng = tanh_(accI[r] + rg*accN[r]);
            float hA = sHf[(grow+r)*HFS + jq];
            float hn = (1.f - zg)*ng + zg*hA;
            sHf[(grow+r)*HFS + jq] = hn;    // own cells: read-then-write, no cross-lane hazard
        }
        __syncthreads();   // barrier 2
    }

    // epilogue: out for step 11
    {
        float h0 = sHf[m*HFS + 4*q + 0];
        float h1 = sHf[m*HFS + 4*q + 1];
        float h2 = sHf[m*HFS + 4*q + 2];
        float h3 = sHf[m*HFS + 4*q + 3];
        float o = h0*wl[0] + h1*wl[1] + h2*wl[2] + h3*wl[3];
        o = sum16(o) + bl;
        if (q == 0) out[b*TT + 11] = o;
    }
}

extern "C" void kernel_launch(void* const* d_in, const int* in_sizes, int n_in,
                              void* d_out, int out_size, void* d_ws, size_t ws_size,
                              hipStream_t stream)
{
    const float* enc  = (const float*)d_in[0];
    const float* hid0 = (const float*)d_in[1];
    const float* lst  = (const float*)d_in[2];
    const float* Wih  = (const float*)d_in[3];
    const float* Whh  = (const float*)d_in[4];
    const float* bih  = (const float*)d_in[5];
    const float* bhh  = (const float*)d_in[6];
    const float* Wlin = (const float*)d_in[7];
    const float* blin = (const float*)d_in[8];
    decoder_kernel<<<BB/16, 256, 0, stream>>>(enc, hid0, lst, Wih, Whh, bih, bhh,
                                              Wlin, blin, (float*)d_out);
}

// Round 8
// 386.758 us; speedup vs baseline: 1.2032x; 1.0878x over previous
//
#include <hip/hip_runtime.h>

// Decoder: 12 sequential steps of {attention over 12 enc timesteps, GRU cell, linear->scalar, feedback}.
// B=65536, block = 16 batch elems, 4 waves. Two layouts per step:
//   phase A (elem-major): lane(q,quad) of wave wv owns elem m=wv*4+quad, dims 4q..4q+3.
//   phase B (row/col):    lane(q,quad) of wave wv owns rows quad*4+r (r=0..3), col jq=wv*16+q.
// R13 = R12 with the cvt_pkrtz type mismatch fixed (builtin returns __fp16x2, not _Float16x2;
// bit-cast wrapper). The experiment is unchanged vs R12:
//  - 13 float divisions/step (sigm x8, tanh x4, inv x1) each compile to the full ~8-instr
//    div_scale/div_fmas/div_fixup sequence without fast-math => ~90 VALU/step. Replaced with
//    __builtin_amdgcn_rcpf (1 instr, ~1ulp; denominators >=1; rcp(inf)=0 saturates correctly).
//  - sHf stride 65 -> 68: rows 16B-aligned => phase-A h readback/write are single b128 ops
//    (was 4x b32 each). Phase-B per-row accesses stay jq-consecutive => conflict-free.
//  - v_cvt_pkrtz_f16_f32 for hi/lo staging (1 instr packs 2; residual algebra is exact
//    regardless of rounding mode). Loop-invariant bias-column constants hoisted to init.
// R11 lessons kept: chunk-major MFMA (no spills at (256,3)), sGh deleted, in-register gates.

#define TT 12     // T_IN == T_OUT == 12
#define BB 65536
#define HH 64
#define SROW 104  // sHi/sLo row stride in halves (52 words, 20 mod 32 banks)
#define HFS 68    // sHf row stride in floats: 272B rows -> 16B-aligned, b128-able in phase A

typedef _Float16 half8 __attribute__((ext_vector_type(8)));
typedef _Float16 half4 __attribute__((ext_vector_type(4)));
typedef _Float16 half2 __attribute__((ext_vector_type(2)));
typedef float    f32x4 __attribute__((ext_vector_type(4)));
typedef float    f32x2 __attribute__((ext_vector_type(2)));

#define L2E 1.44269504088896f

__device__ __forceinline__ float ex2(float x){ return __builtin_amdgcn_exp2f(x); }
__device__ __forceinline__ float rcp_(float x){ return __builtin_amdgcn_rcpf(x); }
// sigm: 4 VALU. tanh: 5 VALU. (vs ~11 each with the compiler's full-precision divide)
__device__ __forceinline__ float sigm(float x){ return rcp_(1.0f + ex2(-L2E*x)); }
__device__ __forceinline__ float tanh_(float x){ return 1.0f - 2.0f*rcp_(ex2(2.0f*L2E*x)+1.0f); }

// v_cvt_pkrtz_f16_f32 returns __fp16x2; bit-cast into our _Float16-based half2 (same layout).
__device__ __forceinline__ half2 pkrtz(float a, float b){
    return __builtin_bit_cast(half2, __builtin_amdgcn_cvt_pkrtz(a, b));
}
__device__ __forceinline__ half4 cat22(half2 a, half2 b){
    return __builtin_shufflevector(a, b, 0, 1, 2, 3);
}

// DPP row_ror rotate-reduce within the 16-lane row (hazard-safe intrinsic form).
template<int N>
__device__ __forceinline__ float ror_add(float x){
    int s = __builtin_amdgcn_update_dpp(0, __float_as_int(x), 0x120+N, 0xF, 0xF, false);
    return x + __int_as_float(s);
}
__device__ __forceinline__ float sum16(float x){
    x = ror_add<1>(x); x = ror_add<2>(x); x = ror_add<4>(x); x = ror_add<8>(x);
    return x;
}

__device__ __forceinline__ float max3f(float a, float b, float c){
    return fmaxf(fmaxf(a,b),c);   // clang folds to v_max3_f32
}

#define MFMA16(A,B,C) __builtin_amdgcn_mfma_f32_16x16x32_f16(A,B,C,0,0,0)

__global__ __launch_bounds__(256, 3)
void decoder_kernel(const float* __restrict__ enc,    // (12,B,64)
                    const float* __restrict__ hid0,   // (B,64)
                    const float* __restrict__ last0,  // (B,3)
                    const float* __restrict__ Wih,    // (192,3)
                    const float* __restrict__ Whh,    // (192,64)
                    const float* __restrict__ bih,    // (192)
                    const float* __restrict__ bhh,    // (192)
                    const float* __restrict__ Wlin,   // (64)
                    const float* __restrict__ blin,   // (1)
                    float* __restrict__ out)          // (B,12)
{
    // A rows: [h_att(64) | l0,l1,l2,1,1 | zero(69..103)] fp16 hi + lo residual.
    __shared__ __align__(16) _Float16 sHi[16*SROW];
    __shared__ __align__(16) _Float16 sLo[16*SROW];
    // fp32 hidden round-trip buffer [16 elems][64 dims], stride 68.
    __shared__ __align__(16) float    sHf[16*HFS];

    const int tid  = threadIdx.x;
    const int wv   = tid >> 6;
    const int lane = tid & 63;
    const int q    = lane & 15;
    const int quad = lane >> 4;
    const int m    = wv*4 + quad;       // phase-A elem, 0..15
    const size_t b = (size_t)blockIdx.x*16 + m;
    const int jq   = wv*16 + q;         // phase-B column, 0..63
    const int grow = quad*4;            // phase-B row base (C/D: row = quad*4 + reg)

    // one-time init: zero pad halves (>=69) of sHi/sLo (stale fp16-NaN would poison MFMA:
    // NaN*0=NaN), and set the loop-invariant bias-column constants at half 68
    // (sHi=1.0 feeds bias_lo column k=68; sLo=0 there). Visible after step-0's barrier 1.
    for (int i = tid; i < 16*SROW; i += 256)
        if ((i % SROW) >= 69){ sHi[i] = (_Float16)0; sLo[i] = (_Float16)0; }
    if (tid < 16){
        sHi[tid*SROW + 68] = (_Float16)1.0f;
        sLo[tid*SROW + 68] = (_Float16)0.0f;
    }

    // ---- one-time loads ----
    f32x4 e4[TT];
    #pragma unroll
    for (int t=0;t<TT;++t)
        e4[t] = *(const f32x4*)(enc + ((size_t)t*BB + b)*HH + 4*q);

    f32x4 h = *(const f32x4*)(hid0 + b*HH + 4*q);          // phase-A hidden (elem-major)
    float l0 = last0[b*3+0], l1 = last0[b*3+1], l2 = last0[b*3+2];
    float bl = blin[0];
    f32x4 wl = *(const f32x4*)(Wlin + 4*q);

    // W_hh^T B-frags, hi/lo fp16 (k-chunks 0,1) per gate. n=lane&15 (col jq), k=kc*32+quad*8+jj.
    half8 bR0h,bR0l,bR1h,bR1l, bZ0h,bZ0l,bZ1h,bZ1l, bN0h,bN0l,bN1h,bN1l;
    {
        #pragma unroll
        for (int g=0; g<3; ++g){
            int row = g*64 + jq;
            #pragma unroll
            for (int kc=0; kc<2; ++kc){
                const float* src = Whh + row*64 + kc*32 + quad*8;
                half8 vh, vl;
                #pragma unroll
                for (int jj=0;jj<8;++jj){
                    float w = src[jj];
                    _Float16 whi = (_Float16)w;
                    vh[jj] = whi;
                    vl[jj] = (_Float16)(w - (float)whi);
                }
                if (g==0){ if(kc==0){bR0h=vh;bR0l=vl;} else {bR1h=vh;bR1l=vl;} }
                else if (g==1){ if(kc==0){bZ0h=vh;bZ0l=vl;} else {bZ1h=vh;bZ1l=vl;} }
                else { if(kc==0){bN0h=vh;bN0l=vl;} else {bN1h=vh;bN1l=vl;} }
            }
        }
    }
    // chunk-2 B-frags: k=64..66 -> Wih cols, k=67 -> bias_hi (A=1), k=68 -> bias_lo (A=1).
    // Only quad==0 lanes (k=64..71) are nonzero.
    half8 bR2, bZ2, bN2, bI2;
    #pragma unroll
    for (int jj=0;jj<8;++jj){ bR2[jj]=(_Float16)0; bZ2[jj]=(_Float16)0; bN2[jj]=(_Float16)0; bI2[jj]=(_Float16)0; }
    if (quad == 0){
        #pragma unroll
        for (int jj=0;jj<3;++jj){
            bR2[jj] = (_Float16)Wih[(      jq)*3 + jj];
            bZ2[jj] = (_Float16)Wih[( 64 + jq)*3 + jj];
            bI2[jj] = (_Float16)Wih[(128 + jq)*3 + jj];
        }
        float br = bih[      jq] + bhh[      jq];
        float bz = bih[ 64 + jq] + bhh[ 64 + jq];
        float bn = bhh[128 + jq];
        float bi = bih[128 + jq];
        _Float16 brh=(_Float16)br, bzh=(_Float16)bz, bnh=(_Float16)bn, bih_=(_Float16)bi;
        bR2[3]=brh; bR2[4]=(_Float16)(br-(float)brh);
        bZ2[3]=bzh; bZ2[4]=(_Float16)(bz-(float)bzh);
        bN2[3]=bnh; bN2[4]=(_Float16)(bn-(float)bnh);
        bI2[3]=bih_; bI2[4]=(_Float16)(bi-(float)bih_);
    }

    // ---- 12 sequential decoder steps ----
    for (int s=0;s<TT;++s){
        // ===== phase A (elem-major) =====
        if (s > 0){
            // read back h' of step s-1 (single b128); emit out[s-1] and feedback.
            h = *(f32x4*)&sHf[m*HFS + 4*q];
            f32x2 po = h.xy * wl.xy;
            po += h.zw * wl.zw;
            float o = sum16(po.x + po.y) + bl;
            if (q == 0) out[b*TT + (s-1)] = o;
            l2 = l1; l1 = l0; l0 = o;
        }
        // attention logits
        float a[TT];
        #pragma unroll
        for (int t=0;t<TT;++t){
            f32x2 p2 = e4[t].xy * h.xy;
            p2 += e4[t].zw * h.zw;
            a[t] = sum16(p2.x + p2.y);
        }
        float m0 = max3f(a[0],a[1],a[2]),  m1 = max3f(a[3],a[4],a[5]);
        float m2 = max3f(a[6],a[7],a[8]),  m3 = max3f(a[9],a[10],a[11]);
        float mx = fmaxf(max3f(m0,m1,m2), m3);
        float nm = -mx*L2E;
        // fused exp + sum + context: a[t] consumed as it is exponentiated (lower reg peak)
        f32x4 ctxA = {0.f,0.f,0.f,0.f}, ctxB = {0.f,0.f,0.f,0.f};
        float ssA = 0.f, ssB = 0.f;
        #pragma unroll
        for (int t=0;t<TT;t+=2){
            float w0 = ex2(__builtin_fmaf(a[t],   L2E, nm));
            float w1 = ex2(__builtin_fmaf(a[t+1], L2E, nm));
            ctxA += e4[t]   * (f32x4)(w0);
            ctxB += e4[t+1] * (f32x4)(w1);
            ssA += w0; ssB += w1;
        }
        float inv = rcp_(ssA + ssB);
        h += (ctxA + ctxB) * (f32x4)(inv);    // h_att

        // stage h_att: fp16 hi (pkrtz) + lo residual (exact remainder, any rounding mode),
        // plus fp32 b128 for the gate z*h term.
        half2 hi01 = pkrtz(h[0], h[1]);
        half2 hi23 = pkrtz(h[2], h[3]);
        half2 lo01 = pkrtz(h[0]-(float)hi01[0], h[1]-(float)hi01[1]);
        half2 lo23 = pkrtz(h[2]-(float)hi23[0], h[3]-(float)hi23[1]);
        *(half4*)&sHi[m*SROW + 4*q] = cat22(hi01, hi23);
        *(half4*)&sLo[m*SROW + 4*q] = cat22(lo01, lo23);
        *(f32x4*)&sHf[m*HFS + 4*q] = h;
        if (q == 0){
            half2 t01 = pkrtz(l0, l1);
            half2 t23 = pkrtz(l2, 1.0f);
            half2 u01 = pkrtz(l0-(float)t01[0], l1-(float)t01[1]);
            half2 u23 = pkrtz(l2-(float)t23[0], 0.0f);
            *(half4*)&sHi[m*SROW + 64] = cat22(t01, t23);
            *(half4*)&sLo[m*SROW + 64] = cat22(u01, u23);
        }
        __syncthreads();   // barrier 1

        // ===== phase B (row/col): chunk-major MFMAs + in-register gates =====
        // A-frag pairs load in their own scope and die after their MFMAs (peak 8 + 16 acc regs).
        f32x4 accR = {0.f,0.f,0.f,0.f};
        f32x4 accZ = {0.f,0.f,0.f,0.f};
        f32x4 accN = {0.f,0.f,0.f,0.f};
        f32x4 accI = {0.f,0.f,0.f,0.f};
        {   // k-chunk 0 (k=0..31)
            half8 ah = *(half8*)&sHi[q*SROW +  0 + quad*8];
            half8 al = *(half8*)&sLo[q*SROW +  0 + quad*8];
            accR = MFMA16(ah,bR0h,accR); accR = MFMA16(ah,bR0l,accR); accR = MFMA16(al,bR0h,accR);
            accZ = MFMA16(ah,bZ0h,accZ); accZ = MFMA16(ah,bZ0l,accZ); accZ = MFMA16(al,bZ0h,accZ);
            accN = MFMA16(ah,bN0h,accN); accN = MFMA16(ah,bN0l,accN); accN = MFMA16(al,bN0h,accN);
        }
        {   // k-chunk 1 (k=32..63)
            half8 ah = *(half8*)&sHi[q*SROW + 32 + quad*8];
            half8 al = *(half8*)&sLo[q*SROW + 32 + quad*8];
            accR = MFMA16(ah,bR1h,accR); accR = MFMA16(ah,bR1l,accR); accR = MFMA16(al,bR1h,accR);
            accZ = MFMA16(ah,bZ1h,accZ); accZ = MFMA16(ah,bZ1l,accZ); accZ = MFMA16(al,bZ1h,accZ);
            accN = MFMA16(ah,bN1h,accN); accN = MFMA16(ah,bN1l,accN); accN = MFMA16(al,bN1h,accN);
        }
        {   // k-chunk 2 (k=64..95): lst + bias columns
            half8 ah = *(half8*)&sHi[q*SROW + 64 + quad*8];
            half8 al = *(half8*)&sLo[q*SROW + 64 + quad*8];
            accR = MFMA16(ah,bR2,accR); accR = MFMA16(al,bR2,accR);
            accZ = MFMA16(ah,bZ2,accZ); accZ = MFMA16(al,bZ2,accZ);
            accN = MFMA16(ah,bN2,accN);
            accI = MFMA16(ah,bI2,accI); accI = MFMA16(al,bI2,accI);
        }

        // gates: r=sig(R), z=sig(Z), n=tanh(I + r*N), h'=(1-z)n+z*h_att
        #pragma unroll
        for (int r=0;r<4;++r){
            float rg = sigm(accR[r]);
            float zg = sigm(accZ[r]);
            float ng = tanh_(accI[r] + rg*accN[r]);
            float hA = sHf[(grow+r)*HFS + jq];
            float hn = (1.f - zg)*ng + zg*hA;
            sHf[(grow+r)*HFS + jq] = hn;    // own cells: read-then-write, no cross-lane hazard
        }
        __syncthreads();   // barrier 2
    }

    // epilogue: out for step 11
    {
        f32x4 hv = *(f32x4*)&sHf[m*HFS + 4*q];
        f32x2 po = hv.xy * wl.xy;
        po += hv.zw * wl.zw;
        float o = sum16(po.x + po.y) + bl;
        if (q == 0) out[b*TT + 11] = o;
    }
}

extern "C" void kernel_launch(void* const* d_in, const int* in_sizes, int n_in,
                              void* d_out, int out_size, void* d_ws, size_t ws_size,
                              hipStream_t stream)
{
    const float* enc  = (const float*)d_in[0];
    const float* hid0 = (const float*)d_in[1];
    const float* lst  = (const float*)d_in[2];
    const float* Wih  = (const float*)d_in[3];
    const float* Whh  = (const float*)d_in[4];
    const float* bih  = (const float*)d_in[5];
    const float* bhh  = (const float*)d_in[6];
    const float* Wlin = (const float*)d_in[7];
    const float* blin = (const float*)d_in[8];
    decoder_kernel<<<BB/16, 256, 0, stream>>>(enc, hid0, lst, Wih, Whh, bih, bhh,
                                              Wlin, blin, (float*)d_out);
}

// Round 9
// 379.717 us; speedup vs baseline: 1.2255x; 1.0185x over previous
//
#include <hip/hip_runtime.h>

// Decoder: 12 sequential steps of {attention over 12 enc timesteps, GRU cell, linear->scalar, feedback}.
// B=65536, block = 16 batch elems, 4 waves. Two layouts per step:
//   phase A (elem-major): lane(q,quad) of wave wv owns elem m=wv*4+quad, dims 4q..4q+3.
//   phase B (row/col):    lane(q,quad) of wave wv owns rows quad*4+r (r=0..3), col jq=wv*16+q.
// R14 = R13 (192us dispatch; VALUBusy 63%, trans ops = 37/step*lane x 8cyc = ~40% of VALU time)
// minus redundant transcendental work + packed gate math:
//  - Lane-specialized softmax exp: after sum16 every lane held ALL 12 logits, and all 16 lanes
//    computed the SAME 12 ex2 -> 16x redundant. Now lane q computes ex2 only for t=q (q<12),
//    ss via sum16, and w[t] is broadcast to the 16-lane group via ds_swizzle BitMode
//    (lane = (l&0x10)|t, offset=(t<<5)|0x10) -- DS pipe, not VALU. 12 ex2 -> 1 per lane.
//  - Gate pre-math packed as f32x4 exprs (v_pk_mul/fma): 44 -> ~32 regular instr/step.
//  - hn = fma(z, hA-n, n) (2 ops vs 3).
// R13 lessons kept: rcp for all divides, b128 sHf (stride 68), pkrtz staging, chunk-major MFMA,
// (256,3), in-register gates, sGh deleted.

#define TT 12     // T_IN == T_OUT == 12
#define BB 65536
#define HH 64
#define SROW 104  // sHi/sLo row stride in halves (52 words, 20 mod 32 banks)
#define HFS 68    // sHf row stride in floats: 272B rows -> 16B-aligned, b128-able in phase A

typedef _Float16 half8 __attribute__((ext_vector_type(8)));
typedef _Float16 half4 __attribute__((ext_vector_type(4)));
typedef _Float16 half2 __attribute__((ext_vector_type(2)));
typedef float    f32x4 __attribute__((ext_vector_type(4)));
typedef float    f32x2 __attribute__((ext_vector_type(2)));

#define L2E 1.44269504088896f

__device__ __forceinline__ float ex2(float x){ return __builtin_amdgcn_exp2f(x); }
__device__ __forceinline__ float rcp_(float x){ return __builtin_amdgcn_rcpf(x); }

// v_cvt_pkrtz_f16_f32 returns __fp16x2; bit-cast into our _Float16-based half2 (same layout).
__device__ __forceinline__ half2 pkrtz(float a, float b){
    return __builtin_bit_cast(half2, __builtin_amdgcn_cvt_pkrtz(a, b));
}
__device__ __forceinline__ half4 cat22(half2 a, half2 b){
    return __builtin_shufflevector(a, b, 0, 1, 2, 3);
}

// DPP row_ror rotate-reduce within the 16-lane row (hazard-safe intrinsic form).
template<int N>
__device__ __forceinline__ float ror_add(float x){
    int s = __builtin_amdgcn_update_dpp(0, __float_as_int(x), 0x120+N, 0xF, 0xF, false);
    return x + __int_as_float(s);
}
__device__ __forceinline__ float sum16(float x){
    x = ror_add<1>(x); x = ror_add<2>(x); x = ror_add<4>(x); x = ror_add<8>(x);
    return x;
}

// Broadcast the value held in lane ((l&0x10)|T) of each 32-lane half to all 16 lanes of its
// group via ds_swizzle BitMode: offset = (xor<<10)|(or<<5)|and with and=0x10, or=T.
template<int T>
__device__ __forceinline__ float bcast16(float x){
    int r = __builtin_amdgcn_ds_swizzle(__float_as_int(x), (T<<5) | 0x10);
    return __int_as_float(r);
}

__device__ __forceinline__ float max3f(float a, float b, float c){
    return fmaxf(fmaxf(a,b),c);   // clang folds to v_max3_f32
}

#define MFMA16(A,B,C) __builtin_amdgcn_mfma_f32_16x16x32_f16(A,B,C,0,0,0)

__global__ __launch_bounds__(256, 3)
void decoder_kernel(const float* __restrict__ enc,    // (12,B,64)
                    const float* __restrict__ hid0,   // (B,64)
                    const float* __restrict__ last0,  // (B,3)
                    const float* __restrict__ Wih,    // (192,3)
                    const float* __restrict__ Whh,    // (192,64)
                    const float* __restrict__ bih,    // (192)
                    const float* __restrict__ bhh,    // (192)
                    const float* __restrict__ Wlin,   // (64)
                    const float* __restrict__ blin,   // (1)
                    float* __restrict__ out)          // (B,12)
{
    // A rows: [h_att(64) | l0,l1,l2,1,1 | zero(69..103)] fp16 hi + lo residual.
    __shared__ __align__(16) _Float16 sHi[16*SROW];
    __shared__ __align__(16) _Float16 sLo[16*SROW];
    // fp32 hidden round-trip buffer [16 elems][64 dims], stride 68.
    __shared__ __align__(16) float    sHf[16*HFS];

    const int tid  = threadIdx.x;
    const int wv   = tid >> 6;
    const int lane = tid & 63;
    const int q    = lane & 15;
    const int quad = lane >> 4;
    const int m    = wv*4 + quad;       // phase-A elem, 0..15
    const size_t b = (size_t)blockIdx.x*16 + m;
    const int jq   = wv*16 + q;         // phase-B column, 0..63
    const int grow = quad*4;            // phase-B row base (C/D: row = quad*4 + reg)

    // one-time init: zero pad halves (>=69) of sHi/sLo (stale fp16-NaN would poison MFMA:
    // NaN*0=NaN), and set the loop-invariant bias-column constants at half 68
    // (sHi=1.0 feeds bias_lo column k=68; sLo=0 there). Visible after step-0's barrier 1.
    for (int i = tid; i < 16*SROW; i += 256)
        if ((i % SROW) >= 69){ sHi[i] = (_Float16)0; sLo[i] = (_Float16)0; }
    if (tid < 16){
        sHi[tid*SROW + 68] = (_Float16)1.0f;
        sLo[tid*SROW + 68] = (_Float16)0.0f;
    }

    // ---- one-time loads ----
    f32x4 e4[TT];
    #pragma unroll
    for (int t=0;t<TT;++t)
        e4[t] = *(const f32x4*)(enc + ((size_t)t*BB + b)*HH + 4*q);

    f32x4 h = *(const f32x4*)(hid0 + b*HH + 4*q);          // phase-A hidden (elem-major)
    float l0 = last0[b*3+0], l1 = last0[b*3+1], l2 = last0[b*3+2];
    float bl = blin[0];
    f32x4 wl = *(const f32x4*)(Wlin + 4*q);

    // W_hh^T B-frags, hi/lo fp16 (k-chunks 0,1) per gate. n=lane&15 (col jq), k=kc*32+quad*8+jj.
    half8 bR0h,bR0l,bR1h,bR1l, bZ0h,bZ0l,bZ1h,bZ1l, bN0h,bN0l,bN1h,bN1l;
    {
        #pragma unroll
        for (int g=0; g<3; ++g){
            int row = g*64 + jq;
            #pragma unroll
            for (int kc=0; kc<2; ++kc){
                const float* src = Whh + row*64 + kc*32 + quad*8;
                half8 vh, vl;
                #pragma unroll
                for (int jj=0;jj<8;++jj){
                    float w = src[jj];
                    _Float16 whi = (_Float16)w;
                    vh[jj] = whi;
                    vl[jj] = (_Float16)(w - (float)whi);
                }
                if (g==0){ if(kc==0){bR0h=vh;bR0l=vl;} else {bR1h=vh;bR1l=vl;} }
                else if (g==1){ if(kc==0){bZ0h=vh;bZ0l=vl;} else {bZ1h=vh;bZ1l=vl;} }
                else { if(kc==0){bN0h=vh;bN0l=vl;} else {bN1h=vh;bN1l=vl;} }
            }
        }
    }
    // chunk-2 B-frags: k=64..66 -> Wih cols, k=67 -> bias_hi (A=1), k=68 -> bias_lo (A=1).
    // Only quad==0 lanes (k=64..71) are nonzero.
    half8 bR2, bZ2, bN2, bI2;
    #pragma unroll
    for (int jj=0;jj<8;++jj){ bR2[jj]=(_Float16)0; bZ2[jj]=(_Float16)0; bN2[jj]=(_Float16)0; bI2[jj]=(_Float16)0; }
    if (quad == 0){
        #pragma unroll
        for (int jj=0;jj<3;++jj){
            bR2[jj] = (_Float16)Wih[(      jq)*3 + jj];
            bZ2[jj] = (_Float16)Wih[( 64 + jq)*3 + jj];
            bI2[jj] = (_Float16)Wih[(128 + jq)*3 + jj];
        }
        float br = bih[      jq] + bhh[      jq];
        float bz = bih[ 64 + jq] + bhh[ 64 + jq];
        float bn = bhh[128 + jq];
        float bi = bih[128 + jq];
        _Float16 brh=(_Float16)br, bzh=(_Float16)bz, bnh=(_Float16)bn, bih_=(_Float16)bi;
        bR2[3]=brh; bR2[4]=(_Float16)(br-(float)brh);
        bZ2[3]=bzh; bZ2[4]=(_Float16)(bz-(float)bzh);
        bN2[3]=bnh; bN2[4]=(_Float16)(bn-(float)bnh);
        bI2[3]=bih_; bI2[4]=(_Float16)(bi-(float)bih_);
    }

    // ---- 12 sequential decoder steps ----
    for (int s=0;s<TT;++s){
        // ===== phase A (elem-major) =====
        if (s > 0){
            // read back h' of step s-1 (single b128); emit out[s-1] and feedback.
            h = *(f32x4*)&sHf[m*HFS + 4*q];
            f32x2 po = h.xy * wl.xy;
            po += h.zw * wl.zw;
            float o = sum16(po.x + po.y) + bl;
            if (q == 0) out[b*TT + (s-1)] = o;
            l2 = l1; l1 = l0; l0 = o;
        }
        // attention logits (all lanes end up holding all 12 via the DPP butterfly)
        float a[TT];
        #pragma unroll
        for (int t=0;t<TT;++t){
            f32x2 p2 = e4[t].xy * h.xy;
            p2 += e4[t].zw * h.zw;
            a[t] = sum16(p2.x + p2.y);
        }
        float m0 = max3f(a[0],a[1],a[2]),  m1 = max3f(a[3],a[4],a[5]);
        float m2 = max3f(a[6],a[7],a[8]),  m3 = max3f(a[9],a[10],a[11]);
        float mx = fmaxf(max3f(m0,m1,m2), m3);
        float nm = -mx*L2E;
        // lane-specialized exp: lane q exponentiates only ITS t=q; others contribute 0.
        float aq = 0.f;
        #pragma unroll
        for (int t=0;t<TT;++t) aq = (q==t) ? a[t] : aq;
        float wq = ex2(__builtin_fmaf(aq, L2E, nm));
        wq = (q < TT) ? wq : 0.f;
        float inv = rcp_(sum16(wq));
        // context: w[t] broadcast back via ds_swizzle (DS pipe), dual f32x4 accumulators
        f32x4 ctxA = {0.f,0.f,0.f,0.f}, ctxB = {0.f,0.f,0.f,0.f};
        #pragma unroll
        for (int t=0;t<TT;t+=2){
            float w0 = bcast16<0>(wq), w1;
            switch(t){  // template-constant swizzle patterns
                case 0:  w0 = bcast16<0>(wq);  w1 = bcast16<1>(wq);  break;
                case 2:  w0 = bcast16<2>(wq);  w1 = bcast16<3>(wq);  break;
                case 4:  w0 = bcast16<4>(wq);  w1 = bcast16<5>(wq);  break;
                case 6:  w0 = bcast16<6>(wq);  w1 = bcast16<7>(wq);  break;
                case 8:  w0 = bcast16<8>(wq);  w1 = bcast16<9>(wq);  break;
                default: w0 = bcast16<10>(wq); w1 = bcast16<11>(wq); break;
            }
            ctxA += e4[t]   * (f32x4)(w0);
            ctxB += e4[t+1] * (f32x4)(w1);
        }
        h += (ctxA + ctxB) * (f32x4)(inv);    // h_att

        // stage h_att: fp16 hi (pkrtz) + lo residual (exact remainder, any rounding mode),
        // plus fp32 b128 for the gate z*h term.
        half2 hi01 = pkrtz(h[0], h[1]);
        half2 hi23 = pkrtz(h[2], h[3]);
        half2 lo01 = pkrtz(h[0]-(float)hi01[0], h[1]-(float)hi01[1]);
        half2 lo23 = pkrtz(h[2]-(float)hi23[0], h[3]-(float)hi23[1]);
        *(half4*)&sHi[m*SROW + 4*q] = cat22(hi01, hi23);
        *(half4*)&sLo[m*SROW + 4*q] = cat22(lo01, lo23);
        *(f32x4*)&sHf[m*HFS + 4*q] = h;
        if (q == 0){
            half2 t01 = pkrtz(l0, l1);
            half2 t23 = pkrtz(l2, 1.0f);
            half2 u01 = pkrtz(l0-(float)t01[0], l1-(float)t01[1]);
            half2 u23 = pkrtz(l2-(float)t23[0], 0.0f);
            *(half4*)&sHi[m*SROW + 64] = cat22(t01, t23);
            *(half4*)&sLo[m*SROW + 64] = cat22(u01, u23);
        }
        __syncthreads();   // barrier 1

        // ===== phase B (row/col): chunk-major MFMAs + in-register gates =====
        // A-frag pairs load in their own scope and die after their MFMAs (peak 8 + 16 acc regs).
        f32x4 accR = {0.f,0.f,0.f,0.f};
        f32x4 accZ = {0.f,0.f,0.f,0.f};
        f32x4 accN = {0.f,0.f,0.f,0.f};
        f32x4 accI = {0.f,0.f,0.f,0.f};
        {   // k-chunk 0 (k=0..31)
            half8 ah = *(half8*)&sHi[q*SROW +  0 + quad*8];
            half8 al = *(half8*)&sLo[q*SROW +  0 + quad*8];
            accR = MFMA16(ah,bR0h,accR); accR = MFMA16(ah,bR0l,accR); accR = MFMA16(al,bR0h,accR);
            accZ = MFMA16(ah,bZ0h,accZ); accZ = MFMA16(ah,bZ0l,accZ); accZ = MFMA16(al,bZ0h,accZ);
            accN = MFMA16(ah,bN0h,accN); accN = MFMA16(ah,bN0l,accN); accN = MFMA16(al,bN0h,accN);
        }
        {   // k-chunk 1 (k=32..63)
            half8 ah = *(half8*)&sHi[q*SROW + 32 + quad*8];
            half8 al = *(half8*)&sLo[q*SROW + 32 + quad*8];
            accR = MFMA16(ah,bR1h,accR); accR = MFMA16(ah,bR1l,accR); accR = MFMA16(al,bR1h,accR);
            accZ = MFMA16(ah,bZ1h,accZ); accZ = MFMA16(ah,bZ1l,accZ); accZ = MFMA16(al,bZ1h,accZ);
            accN = MFMA16(ah,bN1h,accN); accN = MFMA16(ah,bN1l,accN); accN = MFMA16(al,bN1h,accN);
        }
        {   // k-chunk 2 (k=64..95): lst + bias columns
            half8 ah = *(half8*)&sHi[q*SROW + 64 + quad*8];
            half8 al = *(half8*)&sLo[q*SROW + 64 + quad*8];
            accR = MFMA16(ah,bR2,accR); accR = MFMA16(al,bR2,accR);
            accZ = MFMA16(ah,bZ2,accZ); accZ = MFMA16(al,bZ2,accZ);
            accN = MFMA16(ah,bN2,accN);
            accI = MFMA16(ah,bI2,accI); accI = MFMA16(al,bI2,accI);
        }

        // gates (packed pre-math): r=sig(R), z=sig(Z), n=tanh(I + r*N), h'= n + z*(h_att - n)
        f32x4 argR = accR * (f32x4)(-L2E);      // v_pk_mul
        f32x4 argZ = accZ * (f32x4)(-L2E);
        f32x4 rg4, zg4;
        #pragma unroll
        for (int r=0;r<4;++r){
            rg4[r] = rcp_(1.0f + ex2(argR[r]));
            zg4[r] = rcp_(1.0f + ex2(argZ[r]));
        }
        f32x4 targ = (accI + rg4*accN) * (f32x4)(2.0f*L2E);   // pk_fma + pk_mul
        #pragma unroll
        for (int r=0;r<4;++r){
            float ng = 1.0f - 2.0f*rcp_(ex2(targ[r]) + 1.0f);
            float hA = sHf[(grow+r)*HFS + jq];
            float hn = __builtin_fmaf(zg4[r], hA - ng, ng);
            sHf[(grow+r)*HFS + jq] = hn;    // own cells: read-then-write, no cross-lane hazard
        }
        __syncthreads();   // barrier 2
    }

    // epilogue: out for step 11
    {
        f32x4 hv = *(f32x4*)&sHf[m*HFS + 4*q];
        f32x2 po = hv.xy * wl.xy;
        po += hv.zw * wl.zw;
        float o = sum16(po.x + po.y) + bl;
        if (q == 0) out[b*TT + 11] = o;
    }
}

extern "C" void kernel_launch(void* const* d_in, const int* in_sizes, int n_in,
                              void* d_out, int out_size, void* d_ws, size_t ws_size,
                              hipStream_t stream)
{
    const float* enc  = (const float*)d_in[0];
    const float* hid0 = (const float*)d_in[1];
    const float* lst  = (const float*)d_in[2];
    const float* Wih  = (const float*)d_in[3];
    const float* Whh  = (const float*)d_in[4];
    const float* bih  = (const float*)d_in[5];
    const float* bhh  = (const float*)d_in[6];
    const float* Wlin = (const float*)d_in[7];
    const float* blin = (const float*)d_in[8];
    decoder_kernel<<<BB/16, 256, 0, stream>>>(enc, hid0, lst, Wih, Whh, bih, bhh,
                                              Wlin, blin, (float*)d_out);
}